// Round 1
// baseline (718.029 us; speedup 1.0000x reference)
//
#include <hip/hip_runtime.h>

#define NT 512   // T
#define NB 128   // B
#define ND 256   // D
#define NH 256   // H
#define MTILE 64

// ---------------------------------------------------------------------------
// Kernel 1: Z[m][j] = bh[j] + sum_k X[m][k] * Wi[j][k],  m = t*B + b
// One WG per 64-row tile of X; 256 threads; thread j computes column j for
// all 64 rows. X tile staged in LDS (64 KB); Wi rows streamed from L2.
// ---------------------------------------------------------------------------
__global__ __launch_bounds__(256) void zprep_kernel(
    const float* __restrict__ X, const float* __restrict__ Wi,
    const float* __restrict__ bh, float* __restrict__ Z)
{
    __shared__ float xs[MTILE][ND];
    const int m0  = blockIdx.x * MTILE;
    const int tid = threadIdx.x;

    // cooperative stage of X tile: 64*256 floats = 4096 float4, 256 threads
    const float4* xg  = reinterpret_cast<const float4*>(X + (size_t)m0 * ND);
    float4*       xsv = reinterpret_cast<float4*>(&xs[0][0]);
    #pragma unroll
    for (int i = 0; i < (MTILE * ND / 4) / 256; ++i)
        xsv[tid + i * 256] = xg[tid + i * 256];
    __syncthreads();

    const int   j  = tid;
    const float bj = bh[j];
    float acc[MTILE];
    #pragma unroll
    for (int m = 0; m < MTILE; ++m) acc[m] = bj;

    const float* wrow = Wi + (size_t)j * ND;
    for (int k = 0; k < ND; k += 4) {
        const float4 w4 = *reinterpret_cast<const float4*>(wrow + k);
        #pragma unroll
        for (int m = 0; m < MTILE; ++m) {
            const float4 x4 = *reinterpret_cast<const float4*>(&xs[m][k]);
            acc[m] = fmaf(x4.x, w4.x, acc[m]);
            acc[m] = fmaf(x4.y, w4.y, acc[m]);
            acc[m] = fmaf(x4.z, w4.z, acc[m]);
            acc[m] = fmaf(x4.w, w4.w, acc[m]);
        }
    }
    #pragma unroll
    for (int m = 0; m < MTILE; ++m)
        Z[(size_t)(m0 + m) * NH + j] = acc[m];
}

// ---------------------------------------------------------------------------
// Kernel 2: the sequential recurrence. One WG per batch row b (128 WGs).
// 1024 threads: j = tid & 255 (output unit), g = tid >> 8 (k-quarter).
// Each thread keeps Wh[j][g*64 .. g*64+63] in 64 VGPRs.
// Per step: partial dot over 64 k (h broadcast from LDS), 4-way LDS
// reduction, sigmoid, write h back to LDS + global out.
// ZO doubles as Z input and hidden output (same element, read-then-write).
// ---------------------------------------------------------------------------
__global__ __launch_bounds__(1024) void rnn_step_kernel(
    float* __restrict__ ZO,
    const float* __restrict__ h0,
    const float* __restrict__ Wh)
{
    __shared__ float hbuf[NH];
    __shared__ float red[4][NH];
    const int b   = blockIdx.x;
    const int tid = threadIdx.x;
    const int j   = tid & (NH - 1);
    const int g   = tid >> 8;   // 0..3, wave-uniform

    // Wh slice -> registers (one-time, L2-served)
    float w[64];
    const float* wr = Wh + (size_t)j * NH + g * 64;
    #pragma unroll
    for (int i = 0; i < 16; ++i) {
        const float4 w4 = *reinterpret_cast<const float4*>(wr + 4 * i);
        w[4*i+0] = w4.x; w[4*i+1] = w4.y; w[4*i+2] = w4.z; w[4*i+3] = w4.w;
    }
    if (tid < NH) hbuf[tid] = h0[(size_t)b * NH + tid];
    __syncthreads();

    for (int t = 0; t < NT; ++t) {
        float* zrow = ZO + ((size_t)t * NB + b) * NH;
        float  z    = 0.f;
        if (g == 0) z = zrow[j];   // wave-uniform branch; load issued early

        // partial dot over this thread's 64-k slice; 2 chains for ILP
        float p0 = 0.f, p1 = 0.f;
        const float4* hv = reinterpret_cast<const float4*>(&hbuf[g * 64]);
        #pragma unroll
        for (int i = 0; i < 16; i += 2) {
            const float4 a4 = hv[i];
            const float4 b4 = hv[i + 1];
            p0 = fmaf(w[4*i+0], a4.x, p0);
            p0 = fmaf(w[4*i+1], a4.y, p0);
            p0 = fmaf(w[4*i+2], a4.z, p0);
            p0 = fmaf(w[4*i+3], a4.w, p0);
            p1 = fmaf(w[4*i+4], b4.x, p1);
            p1 = fmaf(w[4*i+5], b4.y, p1);
            p1 = fmaf(w[4*i+6], b4.z, p1);
            p1 = fmaf(w[4*i+7], b4.w, p1);
        }
        red[g][j] = p0 + p1;
        __syncthreads();

        if (g == 0) {
            const float a  = z + red[0][j] + red[1][j] + red[2][j] + red[3][j];
            const float hn = 1.0f / (1.0f + __expf(-a));
            hbuf[j] = hn;
            zrow[j] = hn;      // overwrite Z with hidden output
        }
        __syncthreads();
    }
}

extern "C" void kernel_launch(void* const* d_in, const int* in_sizes, int n_in,
                              void* d_out, int out_size, void* d_ws, size_t ws_size,
                              hipStream_t stream) {
    const float* X  = (const float*)d_in[0];
    const float* h0 = (const float*)d_in[1];
    const float* Wi = (const float*)d_in[2];
    const float* Wh = (const float*)d_in[3];
    const float* bh = (const float*)d_in[4];
    float* out = (float*)d_out;

    // Phase 1: Z = X @ Wi^T + bh, staged directly in d_out.
    zprep_kernel<<<(NT * NB) / MTILE, 256, 0, stream>>>(X, Wi, bh, out);
    // Phase 2: sequential recurrence, in-place on d_out.
    rnn_step_kernel<<<NB, 1024, 0, stream>>>(out, h0, Wh);
}

// Round 2
// 471.930 us; speedup vs baseline: 1.5215x; 1.5215x over previous
//
#include <hip/hip_runtime.h>

#define NT 512   // T
#define NB 128   // B
#define ND 256   // D
#define NH 256   // H

// ---------------------------------------------------------------------------
// Phase 1: Z = X @ Wi^T + bh.  Register-tiled fp32 GEMM.
// Grid (M/64, NH/64), 256 threads. Thread (tm,tj) computes a 4x4 sub-tile.
// LDS holds transposed 64x64 chunks of X and Wi (stride 68 to spread banks).
// ---------------------------------------------------------------------------
__global__ __launch_bounds__(256) void zprep_kernel(
    const float* __restrict__ X, const float* __restrict__ Wi,
    const float* __restrict__ bh, float* __restrict__ Z)
{
    __shared__ float xsT[64][68];   // [k][m]
    __shared__ float wsT[64][68];   // [k][j]
    const int tid = threadIdx.x;
    const int tm  = tid & 15, tj = tid >> 4;
    const int m0  = blockIdx.x * 64;
    const int j0  = blockIdx.y * 64;
    const int sm  = tid >> 2, kq = tid & 3;   // staging row / k-quarter

    float acc[4][4] = {};

    for (int c = 0; c < 4; ++c) {            // K = 256 in 4 chunks of 64
        const int k0 = c * 64;
        const float* xr = X  + (size_t)(m0 + sm) * ND + k0 + kq * 16;
        const float* wr = Wi + (size_t)(j0 + sm) * ND + k0 + kq * 16;
        #pragma unroll
        for (int i = 0; i < 4; ++i) {
            const float4 xv = *(const float4*)(xr + i * 4);
            const float4 wv = *(const float4*)(wr + i * 4);
            const int kk = kq * 16 + i * 4;
            xsT[kk + 0][sm] = xv.x; xsT[kk + 1][sm] = xv.y;
            xsT[kk + 2][sm] = xv.z; xsT[kk + 3][sm] = xv.w;
            wsT[kk + 0][sm] = wv.x; wsT[kk + 1][sm] = wv.y;
            wsT[kk + 2][sm] = wv.z; wsT[kk + 3][sm] = wv.w;
        }
        __syncthreads();

        #pragma unroll 8
        for (int k = 0; k < 64; ++k) {
            const float4 x4 = *(const float4*)&xsT[k][tm * 4];
            const float4 w4 = *(const float4*)&wsT[k][tj * 4];
            acc[0][0] = fmaf(x4.x, w4.x, acc[0][0]);
            acc[0][1] = fmaf(x4.x, w4.y, acc[0][1]);
            acc[0][2] = fmaf(x4.x, w4.z, acc[0][2]);
            acc[0][3] = fmaf(x4.x, w4.w, acc[0][3]);
            acc[1][0] = fmaf(x4.y, w4.x, acc[1][0]);
            acc[1][1] = fmaf(x4.y, w4.y, acc[1][1]);
            acc[1][2] = fmaf(x4.y, w4.z, acc[1][2]);
            acc[1][3] = fmaf(x4.y, w4.w, acc[1][3]);
            acc[2][0] = fmaf(x4.z, w4.x, acc[2][0]);
            acc[2][1] = fmaf(x4.z, w4.y, acc[2][1]);
            acc[2][2] = fmaf(x4.z, w4.z, acc[2][2]);
            acc[2][3] = fmaf(x4.z, w4.w, acc[2][3]);
            acc[3][0] = fmaf(x4.w, w4.x, acc[3][0]);
            acc[3][1] = fmaf(x4.w, w4.y, acc[3][1]);
            acc[3][2] = fmaf(x4.w, w4.z, acc[3][2]);
            acc[3][3] = fmaf(x4.w, w4.w, acc[3][3]);
        }
        __syncthreads();
    }

    const float4 b4 = *(const float4*)&bh[j0 + tj * 4];
    #pragma unroll
    for (int r = 0; r < 4; ++r) {
        float4 o;
        o.x = acc[r][0] + b4.x; o.y = acc[r][1] + b4.y;
        o.z = acc[r][2] + b4.z; o.w = acc[r][3] + b4.w;
        *(float4*)&Z[(size_t)(m0 + tm * 4 + r) * NH + j0 + tj * 4] = o;
    }
}

// ---------------------------------------------------------------------------
// Phase 2: recurrence. One WG / batch row, 512 threads (8 waves).
// tid: ks = tid&3 (64-wide k-slice), jb = tid>>2 (pair of outputs j=2jb,2jb+1).
// 128 Wh weights per thread pinned in VGPRs. h double-buffered in LDS
// (stride-68 blocks -> conflict-free broadcast b128 reads). Reduction over
// the 4 k-slices via shfl_xor(1,2). ONE barrier per step. z prefetched t+1.
// ---------------------------------------------------------------------------
__global__ __launch_bounds__(512) void rnn_step_kernel(
    float* __restrict__ ZO,
    const float* __restrict__ h0,
    const float* __restrict__ Wh)
{
    __shared__ float hb[2][272];             // h[k] at [(k>>6)*68 + (k&63)]
    const int b   = blockIdx.x;
    const int tid = threadIdx.x;
    const int ks  = tid & 3;
    const int jb  = tid >> 2;
    const int j0  = jb * 2;

    // Wh slices -> registers, pinned
    float w0[64], w1[64];
    {
        const float* r0 = Wh + (size_t)j0 * NH + ks * 64;
        const float* r1 = r0 + NH;
        #pragma unroll
        for (int i = 0; i < 16; ++i) {
            const float4 a = *(const float4*)(r0 + 4 * i);
            const float4 c = *(const float4*)(r1 + 4 * i);
            w0[4*i+0] = a.x; w0[4*i+1] = a.y; w0[4*i+2] = a.z; w0[4*i+3] = a.w;
            w1[4*i+0] = c.x; w1[4*i+1] = c.y; w1[4*i+2] = c.z; w1[4*i+3] = c.w;
        }
    }
    #pragma unroll
    for (int i = 0; i < 64; ++i) {
        asm volatile("" : "+v"(w0[i]));
        asm volatile("" : "+v"(w1[i]));
    }

    if (tid < NH) hb[0][(tid >> 6) * 68 + (tid & 63)] = h0[(size_t)b * NH + tid];

    // prefetch z for t = 0
    float2 z2 = *(const float2*)(ZO + ((size_t)0 * NB + b) * NH + j0);
    __syncthreads();

    int cur = 0;
    for (int t = 0; t < NT; ++t) {
        // dot over this thread's 64-k slice; 4 chains for ILP
        float a0 = 0.f, a1 = 0.f, b0 = 0.f, b1 = 0.f;
        const float4* hv = (const float4*)&hb[cur][ks * 68];
        #pragma unroll
        for (int i = 0; i < 16; i += 2) {
            const float4 h4 = hv[i];
            const float4 g4 = hv[i + 1];
            a0 = fmaf(w0[4*i+0], h4.x, a0);
            a0 = fmaf(w0[4*i+1], h4.y, a0);
            a0 = fmaf(w0[4*i+2], h4.z, a0);
            a0 = fmaf(w0[4*i+3], h4.w, a0);
            a1 = fmaf(w1[4*i+0], h4.x, a1);
            a1 = fmaf(w1[4*i+1], h4.y, a1);
            a1 = fmaf(w1[4*i+2], h4.z, a1);
            a1 = fmaf(w1[4*i+3], h4.w, a1);
            b0 = fmaf(w0[4*i+4], g4.x, b0);
            b0 = fmaf(w0[4*i+5], g4.y, b0);
            b0 = fmaf(w0[4*i+6], g4.z, b0);
            b0 = fmaf(w0[4*i+7], g4.w, b0);
            b1 = fmaf(w1[4*i+4], g4.x, b1);
            b1 = fmaf(w1[4*i+5], g4.y, b1);
            b1 = fmaf(w1[4*i+6], g4.z, b1);
            b1 = fmaf(w1[4*i+7], g4.w, b1);
        }
        float s0 = a0 + b0;
        float s1 = a1 + b1;

        // prefetch z for t+1 while reduction runs
        float2 z2n = z2;
        if (t + 1 < NT)
            z2n = *(const float2*)(ZO + ((size_t)(t + 1) * NB + b) * NH + j0);

        // reduce the 4 k-slice partials (lanes differing in bits 0,1)
        s0 += __shfl_xor(s0, 1); s1 += __shfl_xor(s1, 1);
        s0 += __shfl_xor(s0, 2); s1 += __shfl_xor(s1, 2);

        if (ks == 0) {
            const float p0 = z2.x + s0;
            const float p1 = z2.y + s1;
            const float h0n = 1.0f / (1.0f + __expf(-p0));
            const float h1n = 1.0f / (1.0f + __expf(-p1));
            *(float2*)&hb[cur ^ 1][(j0 >> 6) * 68 + (j0 & 63)] =
                make_float2(h0n, h1n);
            *(float2*)(ZO + ((size_t)t * NB + b) * NH + j0) =
                make_float2(h0n, h1n);
        }
        z2 = z2n;
        __syncthreads();
        cur ^= 1;
    }
}

extern "C" void kernel_launch(void* const* d_in, const int* in_sizes, int n_in,
                              void* d_out, int out_size, void* d_ws, size_t ws_size,
                              hipStream_t stream) {
    const float* X  = (const float*)d_in[0];
    const float* h0 = (const float*)d_in[1];
    const float* Wi = (const float*)d_in[2];
    const float* Wh = (const float*)d_in[3];
    const float* bh = (const float*)d_in[4];
    float* out = (float*)d_out;

    dim3 zgrid((NT * NB) / 64, NH / 64);
    zprep_kernel<<<zgrid, 256, 0, stream>>>(X, Wi, bh, out);
    rnn_step_kernel<<<NB, 512, 0, stream>>>(out, h0, Wh);
}

// Round 3
// 428.046 us; speedup vs baseline: 1.6775x; 1.1025x over previous
//
#include <hip/hip_runtime.h>

#define NT 512   // T
#define NB 128   // B
#define ND 256   // D
#define NH 256   // H

typedef _Float16 h2 __attribute__((ext_vector_type(2)));

#if __has_builtin(__builtin_amdgcn_fdot2)
#define DOT2(a, b, c) __builtin_amdgcn_fdot2((a), (b), (c), false)
#else
#define DOT2(a, b, c) (fmaf((float)(a).x, (float)(b).x, \
                        fmaf((float)(a).y, (float)(b).y, (c))))
#endif

// ---------------------------------------------------------------------------
// Phase 1: Z = X @ Wi^T + bh.  Register-tiled fp32 GEMM (unchanged from R2).
// ---------------------------------------------------------------------------
__global__ __launch_bounds__(256) void zprep_kernel(
    const float* __restrict__ X, const float* __restrict__ Wi,
    const float* __restrict__ bh, float* __restrict__ Z)
{
    __shared__ float xsT[64][68];   // [k][m]
    __shared__ float wsT[64][68];   // [k][j]
    const int tid = threadIdx.x;
    const int tm  = tid & 15, tj = tid >> 4;
    const int m0  = blockIdx.x * 64;
    const int j0  = blockIdx.y * 64;
    const int sm  = tid >> 2, kq = tid & 3;

    float acc[4][4] = {};

    for (int c = 0; c < 4; ++c) {
        const int k0 = c * 64;
        const float* xr = X  + (size_t)(m0 + sm) * ND + k0 + kq * 16;
        const float* wr = Wi + (size_t)(j0 + sm) * ND + k0 + kq * 16;
        #pragma unroll
        for (int i = 0; i < 4; ++i) {
            const float4 xv = *(const float4*)(xr + i * 4);
            const float4 wv = *(const float4*)(wr + i * 4);
            const int kk = kq * 16 + i * 4;
            xsT[kk + 0][sm] = xv.x; xsT[kk + 1][sm] = xv.y;
            xsT[kk + 2][sm] = xv.z; xsT[kk + 3][sm] = xv.w;
            wsT[kk + 0][sm] = wv.x; wsT[kk + 1][sm] = wv.y;
            wsT[kk + 2][sm] = wv.z; wsT[kk + 3][sm] = wv.w;
        }
        __syncthreads();

        #pragma unroll 8
        for (int k = 0; k < 64; ++k) {
            const float4 x4 = *(const float4*)&xsT[k][tm * 4];
            const float4 w4 = *(const float4*)&wsT[k][tj * 4];
            acc[0][0] = fmaf(x4.x, w4.x, acc[0][0]);
            acc[0][1] = fmaf(x4.x, w4.y, acc[0][1]);
            acc[0][2] = fmaf(x4.x, w4.z, acc[0][2]);
            acc[0][3] = fmaf(x4.x, w4.w, acc[0][3]);
            acc[1][0] = fmaf(x4.y, w4.x, acc[1][0]);
            acc[1][1] = fmaf(x4.y, w4.y, acc[1][1]);
            acc[1][2] = fmaf(x4.y, w4.z, acc[1][2]);
            acc[1][3] = fmaf(x4.y, w4.w, acc[1][3]);
            acc[2][0] = fmaf(x4.z, w4.x, acc[2][0]);
            acc[2][1] = fmaf(x4.z, w4.y, acc[2][1]);
            acc[2][2] = fmaf(x4.z, w4.z, acc[2][2]);
            acc[2][3] = fmaf(x4.z, w4.w, acc[2][3]);
            acc[3][0] = fmaf(x4.w, w4.x, acc[3][0]);
            acc[3][1] = fmaf(x4.w, w4.y, acc[3][1]);
            acc[3][2] = fmaf(x4.w, w4.z, acc[3][2]);
            acc[3][3] = fmaf(x4.w, w4.w, acc[3][3]);
        }
        __syncthreads();
    }

    const float4 b4 = *(const float4*)&bh[j0 + tj * 4];
    #pragma unroll
    for (int r = 0; r < 4; ++r) {
        float4 o;
        o.x = acc[r][0] + b4.x; o.y = acc[r][1] + b4.y;
        o.z = acc[r][2] + b4.z; o.w = acc[r][3] + b4.w;
        *(float4*)&Z[(size_t)(m0 + tm * 4 + r) * NH + j0 + tj * 4] = o;
    }
}

// ---------------------------------------------------------------------------
// Phase 2: recurrence with fp16 dot2, fp32 accumulate.
// One WG / batch row, 512 threads. ks=tid&3 (64-wide k-slice), jb=tid>>2
// (outputs j0=2jb, 2jb+1). 64 packed-half2 weight VGPRs per thread, pinned.
// h double-buffered in LDS as half2 (padded: slice ks at dword ks*36 ->
// banks {0,4,8,12}, conflict-free broadcast). 8 ds_read_b128 + 64 dot2 per
// thread per step, quad shfl_xor reduce, ONE barrier/step, z prefetch t+1.
// launch_bounds(512,2): VGPR cap 256 so weights stay register-resident
// (grid = 128 WGs < 256 CUs, extra occupancy is worthless anyway).
// ---------------------------------------------------------------------------
__global__ __launch_bounds__(512, 2) void rnn_step_kernel(
    float* __restrict__ ZO,
    const float* __restrict__ h0,
    const float* __restrict__ Wh)
{
    __shared__ h2 hb[2][4 * 36];
    const int b   = blockIdx.x;
    const int tid = threadIdx.x;
    const int ks  = tid & 3;
    const int jb  = tid >> 2;
    const int j0  = jb * 2;

    // Wh rows j0, j0+1, k-slice [ks*64, ks*64+64) -> 32+32 packed half2 regs
    h2 w0p[32], w1p[32];
    {
        const float* r0 = Wh + (size_t)j0 * NH + ks * 64;
        const float* r1 = r0 + NH;
        #pragma unroll
        for (int i = 0; i < 16; ++i) {
            const float4 a = *(const float4*)(r0 + 4 * i);
            const float4 c = *(const float4*)(r1 + 4 * i);
            w0p[2*i+0] = h2{(_Float16)a.x, (_Float16)a.y};
            w0p[2*i+1] = h2{(_Float16)a.z, (_Float16)a.w};
            w1p[2*i+0] = h2{(_Float16)c.x, (_Float16)c.y};
            w1p[2*i+1] = h2{(_Float16)c.z, (_Float16)c.w};
        }
    }
    #pragma unroll
    for (int i = 0; i < 32; ++i) {
        asm volatile("" : "+v"(reinterpret_cast<unsigned int&>(w0p[i])));
        asm volatile("" : "+v"(reinterpret_cast<unsigned int&>(w1p[i])));
    }

    if (tid < 128) {
        const float2 hp = *(const float2*)(h0 + (size_t)b * NH + tid * 2);
        hb[0][(tid >> 5) * 36 + (tid & 31)] =
            h2{(_Float16)hp.x, (_Float16)hp.y};
    }

    float2 z2 = *(const float2*)(ZO + (size_t)b * NH + j0);   // t = 0
    __syncthreads();

    int cur = 0;
    for (int t = 0; t < NT; ++t) {
        // read this thread's 32 half2 of h (8 x ds_read_b128)
        h2 hh[32];
        const h2* hv = &hb[cur][ks * 36];
        #pragma unroll
        for (int i = 0; i < 8; ++i)
            *(float4*)&hh[4 * i] = *(const float4*)&hv[4 * i];

        float a0 = 0.f, a1 = 0.f, c0 = 0.f, c1 = 0.f;
        #pragma unroll
        for (int i = 0; i < 16; ++i) {
            a0 = DOT2(w0p[i],      hh[i],      a0);
            a1 = DOT2(w1p[i],      hh[i],      a1);
            c0 = DOT2(w0p[i + 16], hh[i + 16], c0);
            c1 = DOT2(w1p[i + 16], hh[i + 16], c1);
        }
        float s0 = a0 + c0;
        float s1 = a1 + c1;

        // prefetch z for t+1 while the reduce runs
        float2 z2n = z2;
        if (t + 1 < NT)
            z2n = *(const float2*)(ZO + ((size_t)(t + 1) * NB + b) * NH + j0);

        s0 += __shfl_xor(s0, 1); s1 += __shfl_xor(s1, 1);
        s0 += __shfl_xor(s0, 2); s1 += __shfl_xor(s1, 2);

        if (ks == 0) {
            const float p0 = z2.x + s0;
            const float p1 = z2.y + s1;
            const float hn0 = 1.0f / (1.0f + __expf(-p0));
            const float hn1 = 1.0f / (1.0f + __expf(-p1));
            hb[cur ^ 1][(jb >> 5) * 36 + (jb & 31)] =
                h2{(_Float16)hn0, (_Float16)hn1};
            *(float2*)(ZO + ((size_t)t * NB + b) * NH + j0) =
                make_float2(hn0, hn1);
        }
        z2 = z2n;
        __syncthreads();
        cur ^= 1;
    }
}

extern "C" void kernel_launch(void* const* d_in, const int* in_sizes, int n_in,
                              void* d_out, int out_size, void* d_ws, size_t ws_size,
                              hipStream_t stream) {
    const float* X  = (const float*)d_in[0];
    const float* h0 = (const float*)d_in[1];
    const float* Wi = (const float*)d_in[2];
    const float* Wh = (const float*)d_in[3];
    const float* bh = (const float*)d_in[4];
    float* out = (float*)d_out;

    dim3 zgrid((NT * NB) / 64, NH / 64);
    zprep_kernel<<<zgrid, 256, 0, stream>>>(X, Wi, bh, out);
    rnn_step_kernel<<<NB, 512, 0, stream>>>(out, h0, Wh);
}